// Round 4
// baseline (42.934 us; speedup 1.0000x reference)
//
#include <hip/hip_runtime.h>
#include <math.h>

#define BB_ 512
#define NN_ 128
#define DD_ 64
#define NE_ 6
#define NB_ 4

// workspace layout (floats)
#define WS_PAIRE 0                    // 144 floats: pairE[k][ti][tj]
#define WS_AE    144                  // 6
#define WS_ENT   152                  // 6
#define WS_TS    160                  // 64*36*256 stability pair-table
#define WS_TD    (160 + 64 * 36 * 256)  // druglikeness pair-table

// ---------------------------------------------------------------------------
__device__ __forceinline__ float block_reduce256(float v, volatile float* red4,
                                                 int tid) {
#pragma unroll
  for (int off = 32; off > 0; off >>= 1) v += __shfl_down(v, off);
  __syncthreads();
  if ((tid & 63) == 0) red4[tid >> 6] = v;
  __syncthreads();
  return red4[0] + red4[1] + red4[2] + red4[3];
}

// ---------------------------------------------------------------------------
// k_pre: blk 0..127   -> pair-tables T2[m][t1][t2][o] (m=blk>>1, which=blk&1)
//        blk 128      -> zero out[0..1024)
//        blk 129..272 -> pairE entries
//        blk 273      -> ae/ent tables
// ---------------------------------------------------------------------------
__global__ __launch_bounds__(256, 4) void k_pre(
    const float* __restrict__ emb, const float* __restrict__ ae_w,
    const float* __restrict__ ae_b, const float* __restrict__ ent_w,
    const float* __restrict__ ent_b, const float* __restrict__ bW,
    const float* __restrict__ sW1, const float* __restrict__ dW1,
    float* __restrict__ ws, float* __restrict__ out) {
  int blk = blockIdx.x;
  int tid = threadIdx.x;

  if (blk < 128) {
    int m = blk >> 1;     // atom pair index 0..63
    int which = blk & 1;  // 0 stability, 1 druglikeness
    const float* W1 = which ? dW1 : sW1;
    float* T2 = ws + (which ? WS_TD : WS_TS);
    __shared__ float e_s[NE_ * DD_];
    for (int i = tid; i < NE_ * DD_; i += 256) e_s[i] = emb[i];
    __syncthreads();
    int o = tid;
    float a0[NE_] = {0.f, 0.f, 0.f, 0.f, 0.f, 0.f};
    float a1[NE_] = {0.f, 0.f, 0.f, 0.f, 0.f, 0.f};
    const float* W0 = W1 + (size_t)(2 * m) * DD_ * 256 + o;
    const float* Wb = W0 + (size_t)DD_ * 256;
#pragma unroll 8
    for (int d = 0; d < DD_; ++d) {
      float w0 = W0[(size_t)d * 256];
      float w1 = Wb[(size_t)d * 256];
#pragma unroll
      for (int t = 0; t < NE_; ++t) {
        a0[t] += e_s[t * DD_ + d] * w0;
        a1[t] += e_s[t * DD_ + d] * w1;
      }
    }
    float* dst = T2 + (size_t)m * 36 * 256 + o;
#pragma unroll
    for (int t1 = 0; t1 < NE_; ++t1)
#pragma unroll
      for (int t2 = 0; t2 < NE_; ++t2)
        dst[(size_t)(t1 * 6 + t2) * 256] = a0[t1] + a1[t2];
  } else if (blk == 128) {
    float4 z = make_float4(0.f, 0.f, 0.f, 0.f);
    ((float4*)out)[tid] = z;  // 1024 floats: energy + entropy accumulators
  } else if (blk < 273) {
    int e = blk - 129;
    int k = e / 36;
    int rem = e - k * 36;
    int ti = rem / 6, tj = rem - (rem / 6) * 6;
    int d = tid & 63;
    int qd = tid >> 6;
    const float* Wrow = bW + ((size_t)k * DD_ + d) * DD_ + qd * 16;
    const float* xj = emb + tj * DD_ + qd * 16;
    float a = 0.f;
#pragma unroll
    for (int u = 0; u < 16; ++u) a += Wrow[u] * xj[u];
    float c = emb[ti * DD_ + d] * a;
    __shared__ float red4[4];
    c = block_reduce256(c, red4, tid);
    if (tid == 0) ws[WS_PAIRE + e] = c;
  } else {
    int g = tid >> 6, lane = tid & 63;
    for (int idx = g; idx < 12; idx += 4) {
      int t = idx - (idx >= 6 ? 6 : 0);
      bool ent = idx >= 6;
      float c = emb[t * DD_ + lane] * (ent ? ent_w[lane] : ae_w[lane]);
#pragma unroll
      for (int off = 32; off > 0; off >>= 1) c += __shfl_down(c, off);
      if (lane == 0)
        ws[(ent ? WS_ENT : WS_AE) + t] = c + (ent ? ent_b[0] : ae_b[0]);
    }
  }
}

// ---------------------------------------------------------------------------
// k_fused: grid (512, 6), 256 threads.
//   role 0..3: balanced row-pair set of bonds+vdW (+role0 variance)
//   role 4/5 : stability / druglikeness MLP
//   every role writes 1/6 of x
// ---------------------------------------------------------------------------
__global__ __launch_bounds__(256, 4) void k_fused(
    const int* __restrict__ atom_types, const float* __restrict__ pos,
    const int* __restrict__ bonds, const float* __restrict__ emb,
    const float* __restrict__ bb, const float* __restrict__ sb1,
    const float* __restrict__ sW2, const float* __restrict__ sb2,
    const float* __restrict__ sW3, const float* __restrict__ sb3,
    const float* __restrict__ db1, const float* __restrict__ dW2,
    const float* __restrict__ db2, const float* __restrict__ dW3,
    const float* __restrict__ db3, const float* __restrict__ ws,
    float* __restrict__ out) {
  int b = blockIdx.x;
  int role = blockIdx.y;
  int tid = threadIdx.x;

  __shared__ int types[NN_];
  __shared__ float red4[4];
  __shared__ float e_s[NE_ * DD_];

  if (tid < NN_) types[tid] = atom_types[b * NN_ + tid];
  for (int i = tid; i < NE_ * DD_; i += 256) e_s[i] = emb[i];

  if (role < 4) {
    __shared__ float px[NN_], py[NN_], pz[NN_];
    __shared__ float pairE[144];
    __shared__ float aev[NE_], entv[NE_], bbv[NB_];
    for (int i = tid; i < 144; i += 256) pairE[i] = ws[WS_PAIRE + i];
    if (tid < NE_) {
      aev[tid] = ws[WS_AE + tid];
      entv[tid] = ws[WS_ENT + tid];
    }
    if (tid < NB_) bbv[tid] = bb[tid];
    for (int i = tid; i < NN_ * 3; i += 256) {
      float v = pos[(size_t)b * NN_ * 3 + i];
      int n = i / 3, c = i - n * 3;
      if (c == 0) px[n] = v;
      else if (c == 1) py[n] = v;
      else pz[n] = v;
    }
    __syncthreads();

    int q = role;
    // x-write share (1/6 of 2048 float4)
    {
      float4* out4 = (float4*)(out + 2048 + (size_t)b * (NN_ * DD_));
      int lo = role * 341 + (role < 2 ? role : 2);
      int cnt = 341 + (role < 2 ? 1 : 0);
      for (int u = tid; u < cnt; u += 256) {
        int li = lo + u;
        int n = li >> 4;
        int d0 = (li & 15) << 2;
        out4[li] = *(const float4*)&e_s[types[n] * DD_ + d0];
      }
    }

    float ae_p = 0.f, ent_p = 0.f;
    if (tid < 32) {
      int r = tid;
      int i = (r < 16) ? (q * 16 + r) : (112 - q * 16 + r - 16);
      int t = types[i];
      ae_p = aev[t];
      ent_p = entv[t];
    }

    // bonds: balanced row set, triangle-skipped int4 loads
    float bond_p = 0.f;
    {
      const int4* b4 = (const int4*)(bonds + (size_t)b * NN_ * NN_);
#pragma unroll
      for (int it = 0; it < 4; ++it) {
        int li = tid + (it << 8);
        int r = li >> 5;
        int ii = (r < 16) ? (q * 16 + r) : (112 - q * 16 + r - 16);
        int j0 = (li & 31) << 2;
        if (j0 + 3 > ii) {
          int4 v = b4[ii * 32 + (li & 31)];
          int ti6 = types[ii] * 6;
          if (j0 + 0 > ii && v.x > 0)
            bond_p += pairE[(v.x - 1) * 36 + ti6 + types[j0 + 0]] + bbv[v.x - 1];
          if (j0 + 1 > ii && v.y > 0)
            bond_p += pairE[(v.y - 1) * 36 + ti6 + types[j0 + 1]] + bbv[v.y - 1];
          if (j0 + 2 > ii && v.z > 0)
            bond_p += pairE[(v.z - 1) * 36 + ti6 + types[j0 + 2]] + bbv[v.z - 1];
          if (j0 + 3 > ii && v.w > 0)
            bond_p += pairE[(v.w - 1) * 36 + ti6 + types[j0 + 3]] + bbv[v.w - 1];
        }
      }
    }

    // vdW: i fixed per thread (balanced rows), j = (tid&7) + 8*it
    float vdw_p = 0.f;
    {
      int r = tid >> 3;
      int i = (r < 16) ? (q * 16 + r) : (112 - q * 16 + r - 16);
      float pix = px[i], piy = py[i], piz = pz[i];
      int jb = tid & 7;
#pragma unroll 4
      for (int it = 0; it < 16; ++it) {
        int j = jb + (it << 3);
        float dx = pix - px[j];
        float dy = piy - py[j];
        float dz = piz - pz[j];
        float d2 = dx * dx + dy * dy + dz * dz;
        if (j > i && d2 > 0.f) {
          float rcp = __builtin_amdgcn_rcpf(d2);
          float r6 = rcp * rcp * rcp;
          vdw_p += 0.4f * (r6 * r6 - r6);
        }
      }
    }

    float extra = 0.f;
    if (q == 0) {
      float vx = (tid < NN_) ? px[tid] : 0.f;
      float vy = (tid < NN_) ? py[tid] : 0.f;
      float vz = (tid < NN_) ? pz[tid] : 0.f;
      float sx = block_reduce256(vx, red4, tid);
      float sy = block_reduce256(vy, red4, tid);
      float sz = block_reduce256(vz, red4, tid);
      float mx = sx * (1.f / NN_), my = sy * (1.f / NN_), mz = sz * (1.f / NN_);
      float dev = 0.f;
      if (tid < NN_) {
        float a = px[tid] - mx, c = py[tid] - my, e = pz[tid] - mz;
        dev = a * a + c * c + e * e;
      }
      float devsum = block_reduce256(dev, red4, tid);
      if (tid == 0) extra = logf(1.f + devsum * (1.f / (NN_ - 1)));
    }

    float esum = block_reduce256(ae_p + bond_p + vdw_p, red4, tid);
    float ssum = block_reduce256(ent_p, red4, tid);
    if (tid == 0) {
      atomicAdd(&out[b], esum);
      atomicAdd(&out[BB_ + b], ssum + extra);
    }
  } else {
    int which = role - 4;
    __shared__ float h1[256];
    __shared__ float h2[128];
    __shared__ float red[256];
    __shared__ int roff[64];
    __syncthreads();  // types + e_s ready
    if (tid < 64)
      roff[tid] = (tid * 36 + types[2 * tid] * 6 + types[2 * tid + 1]) * 256;

    // x-write share
    {
      float4* out4 = (float4*)(out + 2048 + (size_t)b * (NN_ * DD_));
      int lo = role * 341 + 2;
      for (int u = tid; u < 341; u += 256) {
        int li = lo + u;
        int n = li >> 4;
        int d0 = (li & 15) << 2;
        out4[li] = *(const float4*)&e_s[types[n] * DD_ + d0];
      }
    }
    __syncthreads();  // roff ready

    // layer 1: 64 pair-table gathers, 16-wide batched (uniform rows, L2)
    {
      const float* Tb = ws + (which ? WS_TD : WS_TS) + tid;
      const float* b1 = which ? db1 : sb1;
      float acc = b1[tid];
#pragma unroll
      for (int n0 = 0; n0 < 64; n0 += 16) {
        float v[16];
#pragma unroll
        for (int u = 0; u < 16; ++u) v[u] = Tb[roff[n0 + u]];
        float s = (((v[0] + v[1]) + (v[2] + v[3])) +
                   ((v[4] + v[5]) + (v[6] + v[7]))) +
                  (((v[8] + v[9]) + (v[10] + v[11])) +
                   ((v[12] + v[13]) + (v[14] + v[15])));
        acc += s;
      }
      h1[tid] = fmaxf(acc, 0.f);
    }
    __syncthreads();

    // layer 2: split-K over 2 halves, 16-wide batched
    {
      const float* W2 = which ? dW2 : sW2;
      int k = tid & 127, h = tid >> 7;
      const float* W2p = W2 + (size_t)(h * 128) * 128 + k;
      const float* h1p = h1 + h * 128;
      float acc2 = 0.f;
#pragma unroll
      for (int o0 = 0; o0 < 128; o0 += 16) {
        float w[16];
#pragma unroll
        for (int u = 0; u < 16; ++u) w[u] = W2p[(size_t)(o0 + u) * 128];
        float s = 0.f;
#pragma unroll
        for (int u = 0; u < 16; ++u) s += h1p[o0 + u] * w[u];
        acc2 += s;
      }
      red[tid] = acc2;
    }
    __syncthreads();
    {
      const float* b2 = which ? db2 : sb2;
      if (tid < 128) h2[tid] = fmaxf(b2[tid] + red[tid] + red[tid + 128], 0.f);
    }
    __syncthreads();

    // layer 3 + sigmoid
    {
      const float* W3 = which ? dW3 : sW3;
      float p = (tid < 128) ? h2[tid] * W3[tid] : 0.f;
      float s = block_reduce256(p, red4, tid);
      if (tid == 0) {
        const float* b3 = which ? db3 : sb3;
        out[(2 + which) * BB_ + b] = 1.f / (1.f + __expf(-(s + b3[0])));
      }
    }
  }
}

// ---------------------------------------------------------------------------
extern "C" void kernel_launch(void* const* d_in, const int* in_sizes, int n_in,
                              void* d_out, int out_size, void* d_ws,
                              size_t ws_size, hipStream_t stream) {
  const int* atom_types = (const int*)d_in[0];
  const float* positions = (const float*)d_in[1];
  const int* bonds = (const int*)d_in[2];
  const float* emb = (const float*)d_in[3];
  const float* ae_w = (const float*)d_in[4];
  const float* ae_b = (const float*)d_in[5];
  const float* ent_w = (const float*)d_in[6];
  const float* ent_b = (const float*)d_in[7];
  const float* bW = (const float*)d_in[8];
  const float* bb = (const float*)d_in[9];
  const float* sW1 = (const float*)d_in[10];
  const float* sb1 = (const float*)d_in[11];
  const float* sW2 = (const float*)d_in[12];
  const float* sb2 = (const float*)d_in[13];
  const float* sW3 = (const float*)d_in[14];
  const float* sb3 = (const float*)d_in[15];
  const float* dW1 = (const float*)d_in[16];
  const float* db1 = (const float*)d_in[17];
  const float* dW2 = (const float*)d_in[18];
  const float* db2 = (const float*)d_in[19];
  const float* dW3 = (const float*)d_in[20];
  const float* db3 = (const float*)d_in[21];
  float* out = (float*)d_out;
  float* ws = (float*)d_ws;

  hipLaunchKernelGGL(k_pre, dim3(274), dim3(256), 0, stream, emb, ae_w, ae_b,
                     ent_w, ent_b, bW, sW1, dW1, ws, out);
  hipLaunchKernelGGL(k_fused, dim3(512, 6), dim3(256), 0, stream, atom_types,
                     positions, bonds, emb, bb, sb1, sW2, sb2, sW3, sb3, db1,
                     dW2, db2, dW3, db3, ws, out);
}

// Round 5
// 38.822 us; speedup vs baseline: 1.1059x; 1.1059x over previous
//
#include <hip/hip_runtime.h>
#include <math.h>

#define BB_ 512
#define NN_ 128
#define DD_ 64
#define NE_ 6
#define NB_ 4

// f32 workspace region
#define WS_PAIRE 0    // 144 floats
#define WS_AE    144  // 6
#define WS_ENT   152  // 6
// ushort region starts at float offset 256:
//   [0, 768*256)           stability bf16 table rows (n*6+t)*256 + o
//   [768*256, 1536*256)    druglikeness bf16 table
//   [W2OFF_, +32768)       stability W2 bf16  (o*128+k)
//   [W2OFF_+32768, +32768) druglikeness W2 bf16
#define U16BASE_ 256
#define W2OFF_   (1536 * 256)

__device__ __forceinline__ ushort f2b(float f) {
  unsigned u = __float_as_uint(f);
  u += 0x7FFFu + ((u >> 16) & 1u);
  return (ushort)(u >> 16);
}
__device__ __forceinline__ float b2f(ushort h) {
  return __uint_as_float(((unsigned)h) << 16);
}

// ---------------------------------------------------------------------------
__device__ __forceinline__ float block_reduce256(float v, volatile float* red4,
                                                 int tid) {
#pragma unroll
  for (int off = 32; off > 0; off >>= 1) v += __shfl_down(v, off);
  __syncthreads();
  if ((tid & 63) == 0) red4[tid >> 6] = v;
  __syncthreads();
  return red4[0] + red4[1] + red4[2] + red4[3];
}

// ---------------------------------------------------------------------------
// k_pre: blk 0..511   -> bf16 layer1 tables (n=blk>>2, which=(blk>>1)&1, ohalf)
//        blk 512      -> zero out[0..1024)
//        blk 513..656 -> pairE entries
//        blk 657      -> ae/ent tables
//        blk 658..673 -> W2 bf16 conversion
// ---------------------------------------------------------------------------
__global__ __launch_bounds__(256, 4) void k_pre(
    const float* __restrict__ emb, const float* __restrict__ ae_w,
    const float* __restrict__ ae_b, const float* __restrict__ ent_w,
    const float* __restrict__ ent_b, const float* __restrict__ bW,
    const float* __restrict__ sW1, const float* __restrict__ dW1,
    const float* __restrict__ sW2, const float* __restrict__ dW2,
    float* __restrict__ ws, float* __restrict__ out) {
  int blk = blockIdx.x;
  int tid = threadIdx.x;
  ushort* U = (ushort*)(ws + U16BASE_);

  if (blk < 512) {
    int n = blk >> 2;
    int which = (blk >> 1) & 1;
    int ohalf = blk & 1;
    const float* W1 = which ? dW1 : sW1;
    ushort* T = U + (which ? 768 * 256 : 0);
    __shared__ float e_s[NE_ * DD_];
    __shared__ float part[NE_][128];
    for (int i = tid; i < NE_ * DD_; i += 256) e_s[i] = emb[i];
    __syncthreads();
    int o_local = tid & 127;
    int dhalf = tid >> 7;
    int o = ohalf * 128 + o_local;
    float acc[NE_] = {0.f, 0.f, 0.f, 0.f, 0.f, 0.f};
    const float* Wp = W1 + ((size_t)(n * DD_ + dhalf * 32)) * 256 + o;
#pragma unroll 8
    for (int d = 0; d < 32; ++d) {
      float w = Wp[(size_t)d * 256];
#pragma unroll
      for (int t = 0; t < NE_; ++t) acc[t] += e_s[t * DD_ + dhalf * 32 + d] * w;
    }
    if (dhalf == 1) {
#pragma unroll
      for (int t = 0; t < NE_; ++t) part[t][o_local] = acc[t];
    }
    __syncthreads();
    if (dhalf == 0) {
#pragma unroll
      for (int t = 0; t < NE_; ++t)
        T[(n * NE_ + t) * 256 + o] = f2b(acc[t] + part[t][o_local]);
    }
  } else if (blk == 512) {
    float4 z = make_float4(0.f, 0.f, 0.f, 0.f);
    ((float4*)out)[tid] = z;
  } else if (blk < 657) {
    int e = blk - 513;
    int k = e / 36;
    int rem = e - k * 36;
    int ti = rem / 6, tj = rem - (rem / 6) * 6;
    int d = tid & 63;
    int qd = tid >> 6;
    const float* Wrow = bW + ((size_t)k * DD_ + d) * DD_ + qd * 16;
    const float* xj = emb + tj * DD_ + qd * 16;
    float a = 0.f;
#pragma unroll
    for (int u = 0; u < 16; ++u) a += Wrow[u] * xj[u];
    float c = emb[ti * DD_ + d] * a;
    __shared__ float red4[4];
    c = block_reduce256(c, red4, tid);
    if (tid == 0) ws[WS_PAIRE + e] = c;
  } else if (blk == 657) {
    int g = tid >> 6, lane = tid & 63;
    for (int idx = g; idx < 12; idx += 4) {
      int t = idx - (idx >= 6 ? 6 : 0);
      bool ent = idx >= 6;
      float c = emb[t * DD_ + lane] * (ent ? ent_w[lane] : ae_w[lane]);
#pragma unroll
      for (int off = 32; off > 0; off >>= 1) c += __shfl_down(c, off);
      if (lane == 0)
        ws[(ent ? WS_ENT : WS_AE) + t] = c + (ent ? ent_b[0] : ae_b[0]);
    }
  } else {
    // W2 conversion: 16 blocks x 256 thr x 16 elems = 65536
    int base = (blk - 658) * 4096 + tid;
#pragma unroll
    for (int u = 0; u < 16; ++u) {
      int e = base + u * 256;
      int head = e >> 15;
      int idx = e & 32767;
      const float* src = head ? dW2 : sW2;
      U[W2OFF_ + e] = f2b(src[idx]);
    }
  }
}

// ---------------------------------------------------------------------------
// k_fused: grid (512, 6), 256 threads.
//   role 0..3: balanced row set of bonds+vdW (+role0 variance)
//   role 4/5 : stability / druglikeness MLP (bf16 tables + bf16 W2)
//   every role writes 1/6 of x
// ---------------------------------------------------------------------------
__global__ __launch_bounds__(256, 4) void k_fused(
    const int* __restrict__ atom_types, const float* __restrict__ pos,
    const int* __restrict__ bonds, const float* __restrict__ emb,
    const float* __restrict__ bb, const float* __restrict__ sb1,
    const float* __restrict__ sb2, const float* __restrict__ sW3,
    const float* __restrict__ sb3, const float* __restrict__ db1,
    const float* __restrict__ db2, const float* __restrict__ dW3,
    const float* __restrict__ db3, const float* __restrict__ ws,
    float* __restrict__ out) {
  int b = blockIdx.x;
  int role = blockIdx.y;
  int tid = threadIdx.x;
  const ushort* U = (const ushort*)(ws + U16BASE_);

  __shared__ int types[NN_];
  __shared__ float red4[4];
  __shared__ float e_s[NE_ * DD_];

  if (tid < NN_) types[tid] = atom_types[b * NN_ + tid];
  for (int i = tid; i < NE_ * DD_; i += 256) e_s[i] = emb[i];

  if (role < 4) {
    __shared__ float px[NN_], py[NN_], pz[NN_];
    __shared__ float pairE[144];
    __shared__ float aev[NE_], entv[NE_], bbv[NB_];

    int q = role;
    // ---- early guarded bond loads (overlap staging latency)
    int4 bv[4];
    int bii[4];
    bool bhave[4];
    const int4* b4 = (const int4*)(bonds + (size_t)b * NN_ * NN_);
#pragma unroll
    for (int it = 0; it < 4; ++it) {
      int li = tid + (it << 8);
      int r = li >> 5;
      int ii = (r < 16) ? (q * 16 + r) : (112 - q * 16 + r - 16);
      int j0 = (li & 31) << 2;
      bii[it] = ii;
      bhave[it] = (j0 + 3 > ii);
      if (bhave[it]) bv[it] = b4[ii * 32 + (li & 31)];
    }

    // ---- staging
    for (int i = tid; i < 144; i += 256) pairE[i] = ws[WS_PAIRE + i];
    if (tid < NE_) {
      aev[tid] = ws[WS_AE + tid];
      entv[tid] = ws[WS_ENT + tid];
    }
    if (tid < NB_) bbv[tid] = bb[tid];
    for (int i = tid; i < NN_ * 3; i += 256) {
      float v = pos[(size_t)b * NN_ * 3 + i];
      int n = i / 3, c = i - n * 3;
      if (c == 0) px[n] = v;
      else if (c == 1) py[n] = v;
      else pz[n] = v;
    }
    __syncthreads();

    // ---- x-write share
    {
      float4* out4 = (float4*)(out + 2048 + (size_t)b * (NN_ * DD_));
      int lo = role * 341 + (role < 2 ? role : 2);
      int cnt = 341 + (role < 2 ? 1 : 0);
      for (int u = tid; u < cnt; u += 256) {
        int li = lo + u;
        int n = li >> 4;
        int d0 = (li & 15) << 2;
        out4[li] = *(const float4*)&e_s[types[n] * DD_ + d0];
      }
    }

    float ae_p = 0.f, ent_p = 0.f;
    if (tid < 32) {
      int r = tid;
      int i = (r < 16) ? (q * 16 + r) : (112 - q * 16 + r - 16);
      int t = types[i];
      ae_p = aev[t];
      ent_p = entv[t];
    }

    // ---- consume bonds
    float bond_p = 0.f;
#pragma unroll
    for (int it = 0; it < 4; ++it) {
      if (bhave[it]) {
        int li = tid + (it << 8);
        int ii = bii[it];
        int j0 = (li & 31) << 2;
        int4 v = bv[it];
        int ti6 = types[ii] * 6;
        if (j0 + 0 > ii && v.x > 0)
          bond_p += pairE[(v.x - 1) * 36 + ti6 + types[j0 + 0]] + bbv[v.x - 1];
        if (j0 + 1 > ii && v.y > 0)
          bond_p += pairE[(v.y - 1) * 36 + ti6 + types[j0 + 1]] + bbv[v.y - 1];
        if (j0 + 2 > ii && v.z > 0)
          bond_p += pairE[(v.z - 1) * 36 + ti6 + types[j0 + 2]] + bbv[v.z - 1];
        if (j0 + 3 > ii && v.w > 0)
          bond_p += pairE[(v.w - 1) * 36 + ti6 + types[j0 + 3]] + bbv[v.w - 1];
      }
    }

    // ---- vdW
    float vdw_p = 0.f;
    {
      int r = tid >> 3;
      int i = (r < 16) ? (q * 16 + r) : (112 - q * 16 + r - 16);
      float pix = px[i], piy = py[i], piz = pz[i];
      int jb = tid & 7;
#pragma unroll 4
      for (int it = 0; it < 16; ++it) {
        int j = jb + (it << 3);
        float dx = pix - px[j];
        float dy = piy - py[j];
        float dz = piz - pz[j];
        float d2 = dx * dx + dy * dy + dz * dz;
        if (j > i && d2 > 0.f) {
          float rcp = __builtin_amdgcn_rcpf(d2);
          float r6 = rcp * rcp * rcp;
          vdw_p += 0.4f * (r6 * r6 - r6);
        }
      }
    }

    float extra = 0.f;
    if (q == 0) {
      float vx = (tid < NN_) ? px[tid] : 0.f;
      float vy = (tid < NN_) ? py[tid] : 0.f;
      float vz = (tid < NN_) ? pz[tid] : 0.f;
      float sx = block_reduce256(vx, red4, tid);
      float sy = block_reduce256(vy, red4, tid);
      float sz = block_reduce256(vz, red4, tid);
      float mx = sx * (1.f / NN_), my = sy * (1.f / NN_), mz = sz * (1.f / NN_);
      float dev = 0.f;
      if (tid < NN_) {
        float a = px[tid] - mx, c = py[tid] - my, e = pz[tid] - mz;
        dev = a * a + c * c + e * e;
      }
      float devsum = block_reduce256(dev, red4, tid);
      if (tid == 0) extra = logf(1.f + devsum * (1.f / (NN_ - 1)));
    }

    float esum = block_reduce256(ae_p + bond_p + vdw_p, red4, tid);
    float ssum = block_reduce256(ent_p, red4, tid);
    if (tid == 0) {
      atomicAdd(&out[b], esum);
      atomicAdd(&out[BB_ + b], ssum + extra);
    }
  } else {
    int which = role - 4;
    __shared__ float h1[256];
    __shared__ float h2[128];
    __shared__ float red[256];
    __shared__ int roff[NN_];
    __syncthreads();  // types + e_s ready
    if (tid < NN_) roff[tid] = (tid * NE_ + types[tid]) << 8;  // *256

    // x-write share
    {
      float4* out4 = (float4*)(out + 2048 + (size_t)b * (NN_ * DD_));
      int lo = role * 341 + 2;
      for (int u = tid; u < 341; u += 256) {
        int li = lo + u;
        int n = li >> 4;
        int d0 = (li & 15) << 2;
        out4[li] = *(const float4*)&e_s[types[n] * DD_ + d0];
      }
    }
    __syncthreads();  // roff ready

    // layer 1: 128 bf16-row gathers, 32-wide batched (L2-resident table)
    {
      const ushort* Tb = U + (which ? 768 * 256 : 0) + tid;
      const float* b1 = which ? db1 : sb1;
      float acc = b1[tid];
#pragma unroll
      for (int n0 = 0; n0 < NN_; n0 += 32) {
        ushort v[32];
#pragma unroll
        for (int u = 0; u < 32; ++u) v[u] = Tb[roff[n0 + u]];
        float s = 0.f;
#pragma unroll
        for (int u = 0; u < 32; ++u) s += b2f(v[u]);
        acc += s;
      }
      h1[tid] = fmaxf(acc, 0.f);
    }
    __syncthreads();

    // layer 2: bf16 W2, split-K over 2 halves, 32-wide batched
    {
      const ushort* W2b = U + W2OFF_ + which * 32768;
      int k = tid & 127, h = tid >> 7;
      const ushort* Wp = W2b + (h * 128) * 128 + k;
      const float* h1p = h1 + h * 128;
      float acc2 = 0.f;
#pragma unroll
      for (int o0 = 0; o0 < 128; o0 += 32) {
        ushort w[32];
#pragma unroll
        for (int u = 0; u < 32; ++u) w[u] = Wp[(o0 + u) * 128];
        float s = 0.f;
#pragma unroll
        for (int u = 0; u < 32; ++u) s += h1p[o0 + u] * b2f(w[u]);
        acc2 += s;
      }
      red[tid] = acc2;
    }
    __syncthreads();
    {
      const float* b2 = which ? db2 : sb2;
      if (tid < 128) h2[tid] = fmaxf(b2[tid] + red[tid] + red[tid + 128], 0.f);
    }
    __syncthreads();

    // layer 3 + sigmoid
    {
      const float* W3 = which ? dW3 : sW3;
      float p = (tid < 128) ? h2[tid] * W3[tid] : 0.f;
      float s = block_reduce256(p, red4, tid);
      if (tid == 0) {
        const float* b3 = which ? db3 : sb3;
        out[(2 + which) * BB_ + b] = 1.f / (1.f + __expf(-(s + b3[0])));
      }
    }
  }
}

// ---------------------------------------------------------------------------
extern "C" void kernel_launch(void* const* d_in, const int* in_sizes, int n_in,
                              void* d_out, int out_size, void* d_ws,
                              size_t ws_size, hipStream_t stream) {
  const int* atom_types = (const int*)d_in[0];
  const float* positions = (const float*)d_in[1];
  const int* bonds = (const int*)d_in[2];
  const float* emb = (const float*)d_in[3];
  const float* ae_w = (const float*)d_in[4];
  const float* ae_b = (const float*)d_in[5];
  const float* ent_w = (const float*)d_in[6];
  const float* ent_b = (const float*)d_in[7];
  const float* bW = (const float*)d_in[8];
  const float* bb = (const float*)d_in[9];
  const float* sW1 = (const float*)d_in[10];
  const float* sb1 = (const float*)d_in[11];
  const float* sW2 = (const float*)d_in[12];
  const float* sb2 = (const float*)d_in[13];
  const float* sW3 = (const float*)d_in[14];
  const float* sb3 = (const float*)d_in[15];
  const float* dW1 = (const float*)d_in[16];
  const float* db1 = (const float*)d_in[17];
  const float* dW2 = (const float*)d_in[18];
  const float* db2 = (const float*)d_in[19];
  const float* dW3 = (const float*)d_in[20];
  const float* db3 = (const float*)d_in[21];
  float* out = (float*)d_out;
  float* ws = (float*)d_ws;

  hipLaunchKernelGGL(k_pre, dim3(674), dim3(256), 0, stream, emb, ae_w, ae_b,
                     ent_w, ent_b, bW, sW1, dW1, sW2, dW2, ws, out);
  hipLaunchKernelGGL(k_fused, dim3(512, 6), dim3(256), 0, stream, atom_types,
                     positions, bonds, emb, bb, sb1, sb2, sW3, sb3, db1, db2,
                     dW3, db3, ws, out);
}